// Round 7
// baseline (442.343 us; speedup 1.0000x reference)
//
#include <hip/hip_runtime.h>
#include <hip/hip_bf16.h>
#include <cstdint>
#include <cstddef>

#define NB 32
#define NS 4096
#define NH 512
#define NK 1024   // 2H

typedef __attribute__((ext_vector_type(8))) short short8;
typedef __attribute__((ext_vector_type(4))) float f32x4;

#define SB() __builtin_amdgcn_sched_barrier(0)
#define LGKM0() asm volatile("s_waitcnt lgkmcnt(0)" ::: "memory")
#define VM0() asm volatile("s_waitcnt vmcnt(0)" ::: "memory")
#define BAR() __builtin_amdgcn_s_barrier()

__device__ __forceinline__ unsigned short f2bf_s(float f) {
  union { float f; unsigned u; } x; x.f = f;
  unsigned r = x.u + 0x7fffu + ((x.u >> 16) & 1u);   // RNE bf16
  return (unsigned short)(r >> 16);
}

__device__ __forceinline__ unsigned pk2(float lo, float hi) {
  __hip_bfloat162 h = __float22bfloat162_rn(float2{lo, hi});
  union { __hip_bfloat162 h; unsigned u; } c; c.h = h;
  return c.u;
}

__device__ __forceinline__ void gload16(const void* g, void* l) {
  __builtin_amdgcn_global_load_lds(
      (const __attribute__((address_space(1))) unsigned int*)g,
      (__attribute__((address_space(3))) unsigned int*)l, 16, 0, 0);
}

// ---- kernel 1: pack Ua [512 n][1024 k] f32 -> bf16, pre-swizzled LDS-linear order ----
// layout: [bn(2)][kc(16)][chunk c(2048) of 16B]; c: nloc=c>>3 (0..255), k16=(c&7)^(nloc&7)
// content: bf16 Ua[bn*256+nloc][kc*64 + k16*8 + j], j=0..7   (verified R3)
__global__ void k_ua_pack(const float* __restrict__ ua, unsigned short* __restrict__ out) {
  int t = blockIdx.x * 256 + threadIdx.x;   // 65536 chunks
  int c = t & 2047;
  int kc = (t >> 11) & 15;
  int bn = t >> 15;
  int nloc = c >> 3;
  int k16 = (c & 7) ^ (nloc & 7);
  const float* src = ua + (size_t)(bn * 256 + nloc) * NK + kc * 64 + k16 * 8;
  float4 a = *(const float4*)src;
  float4 b2 = *(const float4*)(src + 4);
  ushort4 o0, o1;
  o0.x = f2bf_s(a.x);  o0.y = f2bf_s(a.y);  o0.z = f2bf_s(a.z);  o0.w = f2bf_s(a.w);
  o1.x = f2bf_s(b2.x); o1.y = f2bf_s(b2.y); o1.z = f2bf_s(b2.z); o1.w = f2bf_s(b2.w);
  ushort4* dst = (ushort4*)(out + (size_t)t * 8);
  dst[0] = o0; dst[1] = o1;
}

// ---- kernel 2: qproj[b][h] = query[b]·Wa_w[h] + Wa_b[h] + Ua_b[h] ----
__global__ void k_qproj(const float* __restrict__ q, const float* __restrict__ ww,
                        const float* __restrict__ wb, const float* __restrict__ ub,
                        float* __restrict__ qp) {
  int b = blockIdx.y;
  int h = blockIdx.x * 128 + threadIdx.x;
  const float* qr = q + b * NH;
  const float* wr = ww + h * NH;
  float acc = 0.f;
  for (int k = 0; k < NH; k += 4) {
    float4 a = *(const float4*)(qr + k);
    float4 c = *(const float4*)(wr + k);
    acc += a.x * c.x + a.y * c.y + a.z * c.z + a.w * c.w;
  }
  qp[b * NH + h] = acc + wb[h] + ub[h];
}

// ---- kernel 3: scores partials, 256x256 tile, 4-phase/K-tile m201-style schedule ----
// grid (16 sblk, 2 bn, 32 b), 512 thr = 8 waves = 2 rg x 4 cg, wave tile 128x64.
// Phases per kc: {reads + stage-slice; barrier; lgkm(0); 16 MFMA; barrier} x4.
// A: reg-staged f32->cvt_pk->LDS (dbuf). B: global_load_lds from pre-swizzled pack (dbuf).
// Only vmem drain: vmcnt(0) at end of ph3 (only B(kc+1) outstanding there).
__global__ __launch_bounds__(512, 2)
void k_scores7(const float* __restrict__ keys, const unsigned short* __restrict__ uapk,
               const float* __restrict__ qproj, const float* __restrict__ vaw,
               float* __restrict__ scores_part) {
  __shared__ alignas(16) unsigned short Albuf[2][256 * 64];  // 2 x 32KB
  __shared__ alignas(16) unsigned short Blbuf[2][256 * 64];  // 2 x 32KB
  __shared__ float qp_s[256];
  __shared__ float va_s[256];
  __shared__ float red[256][4];

  const int sblk = blockIdx.x;
  const int bn   = blockIdx.y;
  const int b    = blockIdx.z;
  const int tid  = threadIdx.x;
  const int w    = tid >> 6;
  const int l    = tid & 63;
  const int rg   = w >> 2;      // 0..1
  const int cg   = w & 3;       // 0..3
  const int l15  = l & 15;
  const int lq   = l >> 4;      // 0..3
  const int asw  = (l15 & 7) << 4;   // read-side swizzle (row&7 == l15&7)

  if (tid < 256) {
    qp_s[tid] = qproj[b * NH + bn * 256 + tid];
    va_s[tid] = vaw[bn * 256 + tid];
  }

  // A staging map (verified R5): srow=tid>>1 (0..255), skh=tid&1 (k-half of 64)
  const int srow = tid >> 1;
  const int skh  = tid & 1;
  const float* agbase = keys + ((size_t)b * NS + sblk * 256 + srow) * NK + skh * 32;
  const int wsw = (srow & 7) << 4;

  // B staging (verified R3): per wave 4 x gload16; src linear == LDS linear
  const char* bgbase = (const char*)uapk + (size_t)bn * 524288 + w * 4096 + l * 16;

  f32x4 acc[8][4];
  #pragma unroll
  for (int i = 0; i < 8; ++i)
    #pragma unroll
    for (int j = 0; j < 4; ++j)
      acc[i][j] = (f32x4){0.f, 0.f, 0.f, 0.f};

  float4 ca0, ca1, ca2, ca3, ca4, ca5, ca6, ca7;

  // ---- prologue: A(0)->regs, B(0)->buf0, cvt+write A(0)->buf0, gate, barrier ----
  ca0 = *(const float4*)(agbase + 0);
  ca1 = *(const float4*)(agbase + 4);
  ca2 = *(const float4*)(agbase + 8);
  ca3 = *(const float4*)(agbase + 12);
  ca4 = *(const float4*)(agbase + 16);
  ca5 = *(const float4*)(agbase + 20);
  ca6 = *(const float4*)(agbase + 24);
  ca7 = *(const float4*)(agbase + 28);
  #pragma unroll
  for (int j2 = 0; j2 < 4; ++j2)
    gload16(bgbase + j2 * 1024, (char*)&Blbuf[0][0] + w * 4096 + j2 * 1024);
  {
    char* Aw = (char*)&Albuf[0][0] + srow * 128;
    uint4 q0, q1, q2, q3;
    q0.x = pk2(ca0.x, ca0.y); q0.y = pk2(ca0.z, ca0.w);
    q0.z = pk2(ca1.x, ca1.y); q0.w = pk2(ca1.z, ca1.w);
    q1.x = pk2(ca2.x, ca2.y); q1.y = pk2(ca2.z, ca2.w);
    q1.z = pk2(ca3.x, ca3.y); q1.w = pk2(ca3.z, ca3.w);
    q2.x = pk2(ca4.x, ca4.y); q2.y = pk2(ca4.z, ca4.w);
    q2.z = pk2(ca5.x, ca5.y); q2.w = pk2(ca5.z, ca5.w);
    q3.x = pk2(ca6.x, ca6.y); q3.y = pk2(ca6.z, ca6.w);
    q3.z = pk2(ca7.x, ca7.y); q3.w = pk2(ca7.z, ca7.w);
    *(uint4*)(Aw + ((skh * 64 +  0) ^ wsw)) = q0;
    *(uint4*)(Aw + ((skh * 64 + 16) ^ wsw)) = q1;
    *(uint4*)(Aw + ((skh * 64 + 32) ^ wsw)) = q2;
    *(uint4*)(Aw + ((skh * 64 + 48) ^ wsw)) = q3;
  }
  VM0();       // B(0) landed (A(0) regs already drained by compiler's own wait)
  LGKM0();     // A writes visible
  SB();
  BAR();

  for (int kc = 0; kc < 16; ++kc) {
    const int cur = kc & 1;
    const char* Ab = (const char*)&Albuf[cur][0];
    const char* Bb = (const char*)&Blbuf[cur][0];
    char* Aw = (char*)&Albuf[cur ^ 1][0] + srow * 128;
    const bool stg = (kc < 15);
    short8 bf[4], af[4];

    // ===== ph0: bf(kk0) + af(h0,kk0); issue A(kc+1)[0..3] =====
    #pragma unroll
    for (int ct = 0; ct < 4; ++ct)
      bf[ct] = *(const short8*)(Bb + (cg * 64 + ct * 16 + l15) * 128 + ((lq * 16) ^ asw));
    #pragma unroll
    for (int r4 = 0; r4 < 4; ++r4)
      af[r4] = *(const short8*)(Ab + (rg * 128 + r4 * 16 + l15) * 128 + ((lq * 16) ^ asw));
    if (stg) {
      const float* ag = agbase + (kc + 1) * 64;
      ca0 = *(const float4*)(ag + 0);
      ca1 = *(const float4*)(ag + 4);
      ca2 = *(const float4*)(ag + 8);
      ca3 = *(const float4*)(ag + 12);
    }
    SB(); BAR(); LGKM0(); SB();
    __builtin_amdgcn_s_setprio(1);
    #pragma unroll
    for (int r4 = 0; r4 < 4; ++r4)
      #pragma unroll
      for (int ct = 0; ct < 4; ++ct)
        acc[r4][ct] = __builtin_amdgcn_mfma_f32_16x16x32_bf16(af[r4], bf[ct], acc[r4][ct], 0, 0, 0);
    __builtin_amdgcn_s_setprio(0);
    SB(); BAR();

    // ===== ph1: af(h1,kk0); issue A(kc+1)[4..7]; MFMA with held bf =====
    #pragma unroll
    for (int r4 = 0; r4 < 4; ++r4)
      af[r4] = *(const short8*)(Ab + (rg * 128 + (4 + r4) * 16 + l15) * 128 + ((lq * 16) ^ asw));
    if (stg) {
      const float* ag = agbase + (kc + 1) * 64;
      ca4 = *(const float4*)(ag + 16);
      ca5 = *(const float4*)(ag + 20);
      ca6 = *(const float4*)(ag + 24);
      ca7 = *(const float4*)(ag + 28);
    }
    SB(); BAR(); LGKM0(); SB();
    __builtin_amdgcn_s_setprio(1);
    #pragma unroll
    for (int r4 = 0; r4 < 4; ++r4)
      #pragma unroll
      for (int ct = 0; ct < 4; ++ct)
        acc[4 + r4][ct] = __builtin_amdgcn_mfma_f32_16x16x32_bf16(af[r4], bf[ct], acc[4 + r4][ct], 0, 0, 0);
    __builtin_amdgcn_s_setprio(0);
    SB(); BAR();

    // ===== ph2: bf(kk1) + af(h0,kk1); issue B(kc+1) gload_lds into buf^1 =====
    #pragma unroll
    for (int ct = 0; ct < 4; ++ct)
      bf[ct] = *(const short8*)(Bb + (cg * 64 + ct * 16 + l15) * 128 + ((64 + lq * 16) ^ asw));
    #pragma unroll
    for (int r4 = 0; r4 < 4; ++r4)
      af[r4] = *(const short8*)(Ab + (rg * 128 + r4 * 16 + l15) * 128 + ((64 + lq * 16) ^ asw));
    if (stg) {
      const char* bg = bgbase + (size_t)(kc + 1) * 32768;
      #pragma unroll
      for (int j2 = 0; j2 < 4; ++j2)
        gload16(bg + j2 * 1024, (char*)&Blbuf[cur ^ 1][0] + w * 4096 + j2 * 1024);
    }
    SB(); BAR(); LGKM0(); SB();
    __builtin_amdgcn_s_setprio(1);
    #pragma unroll
    for (int r4 = 0; r4 < 4; ++r4)
      #pragma unroll
      for (int ct = 0; ct < 4; ++ct)
        acc[r4][ct] = __builtin_amdgcn_mfma_f32_16x16x32_bf16(af[r4], bf[ct], acc[r4][ct], 0, 0, 0);
    __builtin_amdgcn_s_setprio(0);
    SB(); BAR();

    // ===== ph3: af(h1,kk1); cvt+ds_write A(kc+1)->buf^1; vmcnt(0) B-gate =====
    #pragma unroll
    for (int r4 = 0; r4 < 4; ++r4)
      af[r4] = *(const short8*)(Ab + (rg * 128 + (4 + r4) * 16 + l15) * 128 + ((64 + lq * 16) ^ asw));
    if (stg) {
      uint4 q0, q1, q2, q3;
      q0.x = pk2(ca0.x, ca0.y); q0.y = pk2(ca0.z, ca0.w);
      q0.z = pk2(ca1.x, ca1.y); q0.w = pk2(ca1.z, ca1.w);
      q1.x = pk2(ca2.x, ca2.y); q1.y = pk2(ca2.z, ca2.w);
      q1.z = pk2(ca3.x, ca3.y); q1.w = pk2(ca3.z, ca3.w);
      q2.x = pk2(ca4.x, ca4.y); q2.y = pk2(ca4.z, ca4.w);
      q2.z = pk2(ca5.x, ca5.y); q2.w = pk2(ca5.z, ca5.w);
      q3.x = pk2(ca6.x, ca6.y); q3.y = pk2(ca6.z, ca6.w);
      q3.z = pk2(ca7.x, ca7.y); q3.w = pk2(ca7.z, ca7.w);
      *(uint4*)(Aw + ((skh * 64 +  0) ^ wsw)) = q0;
      *(uint4*)(Aw + ((skh * 64 + 16) ^ wsw)) = q1;
      *(uint4*)(Aw + ((skh * 64 + 32) ^ wsw)) = q2;
      *(uint4*)(Aw + ((skh * 64 + 48) ^ wsw)) = q3;
      VM0();   // only B(kc+1) outstanding here (A consumed by cvt): gate before barrier
    }
    LGKM0();   // my ds_writes visible before crossing
    SB(); BAR(); LGKM0(); SB();
    __builtin_amdgcn_s_setprio(1);
    #pragma unroll
    for (int r4 = 0; r4 < 4; ++r4)
      #pragma unroll
      for (int ct = 0; ct < 4; ++ct)
        acc[4 + r4][ct] = __builtin_amdgcn_mfma_f32_16x16x32_bf16(af[r4], bf[ct], acc[4 + r4][ct], 0, 0, 0);
    __builtin_amdgcn_s_setprio(0);
    SB(); BAR();
  }

  // ---- epilogue (verified R3): partial score over this block's 256 n-cols ----
  #pragma unroll
  for (int rt = 0; rt < 8; ++rt) {
    #pragma unroll
    for (int reg = 0; reg < 4; ++reg) {
      float sum = 0.f;
      #pragma unroll
      for (int ct = 0; ct < 4; ++ct) {
        int gn = cg * 64 + ct * 16 + l15;
        float x = qp_s[gn] + acc[rt][ct][reg];
        float e = __expf(2.f * x);
        float th = 1.f - __fdividef(2.f, e + 1.f);
        sum += va_s[gn] * th;
      }
      sum += __shfl_xor(sum, 1);
      sum += __shfl_xor(sum, 2);
      sum += __shfl_xor(sum, 4);
      sum += __shfl_xor(sum, 8);
      if (l15 == 0)
        red[rg * 128 + rt * 16 + lq * 4 + reg][cg] = sum;
    }
  }
  __syncthreads();
  if (tid < 256) {
    float s = red[tid][0] + red[tid][1] + red[tid][2] + red[tid][3];
    scores_part[((size_t)bn * NB + b) * NS + sblk * 256 + tid] = s;
  }
}

// ---- kernel 4: softmax over (part0 + part1 + vab) -> attn out ----
__global__ void k_softmax(const float* __restrict__ sp, const float* __restrict__ vab,
                          float* __restrict__ attn) {
  __shared__ float redm[4];
  __shared__ float reds[4];
  int b = blockIdx.x, tid = threadIdx.x;
  const float* r0 = sp + (size_t)b * NS;
  const float* r1 = sp + (size_t)(NB + b) * NS;
  float vb = vab[0];
  float v[16];
  float m = -1e30f;
  #pragma unroll
  for (int i = 0; i < 16; ++i) {
    int idx = i * 256 + tid;
    v[i] = r0[idx] + r1[idx] + vb;
    m = fmaxf(m, v[i]);
  }
  #pragma unroll
  for (int off = 1; off < 64; off <<= 1) m = fmaxf(m, __shfl_xor(m, off));
  if ((tid & 63) == 0) redm[tid >> 6] = m;
  __syncthreads();
  m = fmaxf(fmaxf(redm[0], redm[1]), fmaxf(redm[2], redm[3]));
  float s = 0.f;
  #pragma unroll
  for (int i = 0; i < 16; ++i) { v[i] = expf(v[i] - m); s += v[i]; }
  #pragma unroll
  for (int off = 1; off < 64; off <<= 1) s += __shfl_xor(s, off);
  if ((tid & 63) == 0) reds[tid >> 6] = s;
  __syncthreads();
  s = reds[0] + reds[1] + reds[2] + reds[3];
  float inv = 1.f / s;
  float* o = attn + (size_t)b * NS;
  #pragma unroll
  for (int i = 0; i < 16; ++i) o[i * 256 + tid] = v[i] * inv;
}

// ---- kernel 5: context partials (8 segments of 512 s-rows) ----
__global__ void k_ctx_partial(const float* __restrict__ keys, const float* __restrict__ attn,
                              float* __restrict__ part) {
  __shared__ float w_s[512];
  int b = blockIdx.y, seg = blockIdx.x, tid = threadIdx.x;
  int sbeg = seg * 512;
  w_s[tid] = attn[(size_t)b * NS + sbeg + tid];
  w_s[tid + 256] = attn[(size_t)b * NS + sbeg + 256 + tid];
  __syncthreads();
  const float* kp = keys + ((size_t)b * NS + sbeg) * NK + tid * 4;
  float ax = 0.f, ay = 0.f, az = 0.f, aw = 0.f;
  #pragma unroll 4
  for (int s = 0; s < 512; ++s) {
    float4 kv = *(const float4*)(kp + (size_t)s * NK);
    float wv = w_s[s];
    ax += wv * kv.x; ay += wv * kv.y; az += wv * kv.z; aw += wv * kv.w;
  }
  float4 o; o.x = ax; o.y = ay; o.z = az; o.w = aw;
  *(float4*)(part + ((size_t)(seg * NB + b) << 10) + tid * 4) = o;
}

// ---- kernel 6: reduce 8 segment partials -> context ----
__global__ void k_ctx_reduce(const float* __restrict__ part, float* __restrict__ ctx) {
  int i = blockIdx.x * 256 + threadIdx.x;   // 32768
  int b = i >> 10, c = i & 1023;
  float s = 0.f;
  #pragma unroll
  for (int seg = 0; seg < 8; ++seg) s += part[((size_t)(seg * NB + b) << 10) + c];
  ctx[i] = s;
}

extern "C" void kernel_launch(void* const* d_in, const int* in_sizes, int n_in,
                              void* d_out, int out_size, void* d_ws, size_t ws_size,
                              hipStream_t stream) {
  const float* query = (const float*)d_in[0];
  const float* keys  = (const float*)d_in[1];
  const float* Wa_w  = (const float*)d_in[2];
  const float* Wa_b  = (const float*)d_in[3];
  const float* Ua_w  = (const float*)d_in[4];
  const float* Ua_b  = (const float*)d_in[5];
  const float* Va_w  = (const float*)d_in[6];
  const float* Va_b  = (const float*)d_in[7];

  float* out      = (float*)d_out;
  float* ctx_out  = out;             // [32][1024]
  float* attn_out = out + NB * NK;   // [32][4096]

  unsigned short* ua_pk = (unsigned short*)d_ws;                       // 1 MB
  float* qproj  = (float*)((char*)d_ws + (1u << 20));                  // 64 KB
  float* spart  = (float*)((char*)d_ws + (1u << 20) + (1u << 16));     // 1 MB (2 partials)
  float* part   = (float*)((char*)d_ws + (2u << 20) + (1u << 16));     // 1 MB

  k_ua_pack<<<256, 256, 0, stream>>>(Ua_w, ua_pk);
  k_qproj<<<dim3(4, NB), 128, 0, stream>>>(query, Wa_w, Wa_b, Ua_b, qproj);
  k_scores7<<<dim3(16, 2, NB), 512, 0, stream>>>(keys, ua_pk, qproj, Va_w, spart);
  k_softmax<<<NB, 256, 0, stream>>>(spart, Va_b, attn_out);
  k_ctx_partial<<<dim3(8, NB), 256, 0, stream>>>(keys, attn_out, part);
  k_ctx_reduce<<<NB * NK / 256, 256, 0, stream>>>(part, ctx_out);
}

// Round 8
// 439.737 us; speedup vs baseline: 1.0059x; 1.0059x over previous
//
#include <hip/hip_runtime.h>
#include <hip/hip_bf16.h>
#include <cstdint>
#include <cstddef>

#define NB 32
#define NS 4096
#define NH 512
#define NK 1024   // 2H

typedef __attribute__((ext_vector_type(8))) short short8;
typedef __attribute__((ext_vector_type(4))) float f32x4;

#define SB() __builtin_amdgcn_sched_barrier(0)
#define LGKM0() asm volatile("s_waitcnt lgkmcnt(0)" ::: "memory")
#define VM0() asm volatile("s_waitcnt vmcnt(0)" ::: "memory")
#define BAR() __builtin_amdgcn_s_barrier()

__device__ __forceinline__ unsigned short f2bf_s(float f) {
  union { float f; unsigned u; } x; x.f = f;
  unsigned r = x.u + 0x7fffu + ((x.u >> 16) & 1u);   // RNE bf16
  return (unsigned short)(r >> 16);
}

__device__ __forceinline__ unsigned pk2(float lo, float hi) {
  __hip_bfloat162 h = __float22bfloat162_rn(float2{lo, hi});
  union { __hip_bfloat162 h; unsigned u; } c; c.h = h;
  return c.u;
}

__device__ __forceinline__ void gload16(const void* g, void* l) {
  __builtin_amdgcn_global_load_lds(
      (const __attribute__((address_space(1))) unsigned int*)g,
      (__attribute__((address_space(3))) unsigned int*)l, 16, 0, 0);
}

// ---- kernel 1: pack Ua [512 n][1024 k] f32 -> bf16, pre-swizzled LDS-linear (R3-verified) ----
// layout: [bn(2)][kc(16)][chunk c(2048) of 16B]; c: nloc=c>>3 (0..255), k16=(c&7)^(nloc&7)
__global__ void k_ua_pack(const float* __restrict__ ua, unsigned short* __restrict__ out) {
  int t = blockIdx.x * 256 + threadIdx.x;   // 65536 chunks
  int c = t & 2047;
  int kc = (t >> 11) & 15;
  int bn = t >> 15;
  int nloc = c >> 3;
  int k16 = (c & 7) ^ (nloc & 7);
  const float* src = ua + (size_t)(bn * 256 + nloc) * NK + kc * 64 + k16 * 8;
  float4 a = *(const float4*)src;
  float4 b2 = *(const float4*)(src + 4);
  ushort4 o0, o1;
  o0.x = f2bf_s(a.x);  o0.y = f2bf_s(a.y);  o0.z = f2bf_s(a.z);  o0.w = f2bf_s(a.w);
  o1.x = f2bf_s(b2.x); o1.y = f2bf_s(b2.y); o1.z = f2bf_s(b2.z); o1.w = f2bf_s(b2.w);
  ushort4* dst = (ushort4*)(out + (size_t)t * 8);
  dst[0] = o0; dst[1] = o1;
}

// ---- kernel 1b: pack keys [B*S rows][1024 k] f32 -> bf16, same pre-swizzled layout ----
// layout: [sb(512) = b*16+sblk][kc(16)][chunk c(2048) of 16B]; row = sb*256 + (c>>3)
__global__ void k_keys_pack(const float* __restrict__ keys, unsigned short* __restrict__ out) {
  size_t t = (size_t)blockIdx.x * 256 + threadIdx.x;   // 16,777,216 chunks of 16B
  int c    = (int)(t & 2047);
  int kc   = (int)((t >> 11) & 15);
  int sb   = (int)(t >> 15);       // 0..511
  int nloc = c >> 3;
  int k16  = (c & 7) ^ (nloc & 7);
  const float* src = keys + ((size_t)sb * 256 + nloc) * NK + kc * 64 + k16 * 8;
  float4 a  = *(const float4*)src;
  float4 b2 = *(const float4*)(src + 4);
  uint4 o;
  o.x = pk2(a.x, a.y);  o.y = pk2(a.z, a.w);
  o.z = pk2(b2.x, b2.y); o.w = pk2(b2.z, b2.w);
  *(uint4*)(out + t * 8) = o;
}

// ---- kernel 2: qproj[b][h] = query[b]·Wa_w[h] + Wa_b[h] + Ua_b[h] ----
__global__ void k_qproj(const float* __restrict__ q, const float* __restrict__ ww,
                        const float* __restrict__ wb, const float* __restrict__ ub,
                        float* __restrict__ qp) {
  int b = blockIdx.y;
  int h = blockIdx.x * 128 + threadIdx.x;
  const float* qr = q + b * NH;
  const float* wr = ww + h * NH;
  float acc = 0.f;
  for (int k = 0; k < NH; k += 4) {
    float4 a = *(const float4*)(qr + k);
    float4 c = *(const float4*)(wr + k);
    acc += a.x * c.x + a.y * c.y + a.z * c.z + a.w * c.w;
  }
  qp[b * NH + h] = acc + wb[h] + ub[h];
}

// ---- kernel 3 (NEW): pure-bf16 scores GEMM, both operands via global_load_lds ----
// grid (16 sblk, 2 bn, 32 b), 512 thr = 8 waves = 2 rg x 4 cg, wave tile 128x64.
// A from keys_pk (pre-swizzled bf16), B from ua_pk. dbuf both. 4 phases/kc, 16 MFMA each.
// Stage: ph0 issues A(kc+1) (4 gload16/wave), ph1 issues B(kc+1); single vmcnt(0) gate at
// end of ph3 — every awaited load was issued >=2 phases (~2000cyc) earlier.
__global__ __launch_bounds__(512, 1)
void k_scores8(const unsigned short* __restrict__ keyspk, const unsigned short* __restrict__ uapk,
               const float* __restrict__ qproj, const float* __restrict__ vaw,
               float* __restrict__ scores_part) {
  __shared__ alignas(16) unsigned short Albuf[2][256 * 64];  // 2 x 32KB
  __shared__ alignas(16) unsigned short Blbuf[2][256 * 64];  // 2 x 32KB
  __shared__ float qp_s[256];
  __shared__ float va_s[256];
  __shared__ float red[256][4];

  const int sblk = blockIdx.x;
  const int bn   = blockIdx.y;
  const int b    = blockIdx.z;
  const int tid  = threadIdx.x;
  const int w    = tid >> 6;
  const int l    = tid & 63;
  const int rg   = w >> 2;      // 0..1
  const int cg   = w & 3;       // 0..3
  const int l15  = l & 15;
  const int lq   = l >> 4;      // 0..3
  const int asw  = (l15 & 7) << 4;   // read-side swizzle (row&7 == l15&7)

  if (tid < 256) {
    qp_s[tid] = qproj[b * NH + bn * 256 + tid];
    va_s[tid] = vaw[bn * 256 + tid];
  }

  // A: per (b,sblk) 512KB pack; per kc 32KB; per wave 4 x gload16 (1KB each)
  const char* agbase = (const char*)keyspk + ((size_t)(b * 16 + sblk)) * 524288 + w * 4096 + l * 16;
  // B: per bn 512KB pack; per kc 32KB; per wave 4 x gload16
  const char* bgbase = (const char*)uapk + (size_t)bn * 524288 + w * 4096 + l * 16;

  f32x4 acc[8][4];
  #pragma unroll
  for (int i = 0; i < 8; ++i)
    #pragma unroll
    for (int j = 0; j < 4; ++j)
      acc[i][j] = (f32x4){0.f, 0.f, 0.f, 0.f};

  // ---- prologue: stage kc=0 into buf0 (A+B), gate, barrier ----
  #pragma unroll
  for (int j2 = 0; j2 < 4; ++j2)
    gload16(agbase + j2 * 1024, (char*)&Albuf[0][0] + w * 4096 + j2 * 1024);
  #pragma unroll
  for (int j2 = 0; j2 < 4; ++j2)
    gload16(bgbase + j2 * 1024, (char*)&Blbuf[0][0] + w * 4096 + j2 * 1024);
  VM0();
  LGKM0();
  SB();
  BAR();

  for (int kc = 0; kc < 16; ++kc) {
    const int cur = kc & 1;
    const char* Ab = (const char*)&Albuf[cur][0];
    const char* Bb = (const char*)&Blbuf[cur][0];
    const bool stg = (kc < 15);
    short8 bf[4], af[4];

    // ===== ph0: bf(kk0) + af(h0,kk0); issue A(kc+1) gloads into buf^1 =====
    #pragma unroll
    for (int ct = 0; ct < 4; ++ct)
      bf[ct] = *(const short8*)(Bb + (cg * 64 + ct * 16 + l15) * 128 + ((lq * 16) ^ asw));
    #pragma unroll
    for (int r4 = 0; r4 < 4; ++r4)
      af[r4] = *(const short8*)(Ab + (rg * 128 + r4 * 16 + l15) * 128 + ((lq * 16) ^ asw));
    if (stg) {
      const char* ag = agbase + (size_t)(kc + 1) * 32768;
      #pragma unroll
      for (int j2 = 0; j2 < 4; ++j2)
        gload16(ag + j2 * 1024, (char*)&Albuf[cur ^ 1][0] + w * 4096 + j2 * 1024);
    }
    SB(); BAR(); LGKM0(); SB();
    __builtin_amdgcn_s_setprio(1);
    #pragma unroll
    for (int r4 = 0; r4 < 4; ++r4)
      #pragma unroll
      for (int ct = 0; ct < 4; ++ct)
        acc[r4][ct] = __builtin_amdgcn_mfma_f32_16x16x32_bf16(af[r4], bf[ct], acc[r4][ct], 0, 0, 0);
    __builtin_amdgcn_s_setprio(0);
    SB(); BAR();

    // ===== ph1: af(h1,kk0); issue B(kc+1) gloads into buf^1; MFMA with held bf =====
    #pragma unroll
    for (int r4 = 0; r4 < 4; ++r4)
      af[r4] = *(const short8*)(Ab + (rg * 128 + (4 + r4) * 16 + l15) * 128 + ((lq * 16) ^ asw));
    if (stg) {
      const char* bg = bgbase + (size_t)(kc + 1) * 32768;
      #pragma unroll
      for (int j2 = 0; j2 < 4; ++j2)
        gload16(bg + j2 * 1024, (char*)&Blbuf[cur ^ 1][0] + w * 4096 + j2 * 1024);
    }
    SB(); BAR(); LGKM0(); SB();
    __builtin_amdgcn_s_setprio(1);
    #pragma unroll
    for (int r4 = 0; r4 < 4; ++r4)
      #pragma unroll
      for (int ct = 0; ct < 4; ++ct)
        acc[4 + r4][ct] = __builtin_amdgcn_mfma_f32_16x16x32_bf16(af[r4], bf[ct], acc[4 + r4][ct], 0, 0, 0);
    __builtin_amdgcn_s_setprio(0);
    SB(); BAR();

    // ===== ph2: bf(kk1) + af(h0,kk1) =====
    #pragma unroll
    for (int ct = 0; ct < 4; ++ct)
      bf[ct] = *(const short8*)(Bb + (cg * 64 + ct * 16 + l15) * 128 + ((64 + lq * 16) ^ asw));
    #pragma unroll
    for (int r4 = 0; r4 < 4; ++r4)
      af[r4] = *(const short8*)(Ab + (rg * 128 + r4 * 16 + l15) * 128 + ((64 + lq * 16) ^ asw));
    SB(); BAR(); LGKM0(); SB();
    __builtin_amdgcn_s_setprio(1);
    #pragma unroll
    for (int r4 = 0; r4 < 4; ++r4)
      #pragma unroll
      for (int ct = 0; ct < 4; ++ct)
        acc[r4][ct] = __builtin_amdgcn_mfma_f32_16x16x32_bf16(af[r4], bf[ct], acc[r4][ct], 0, 0, 0);
    __builtin_amdgcn_s_setprio(0);
    SB(); BAR();

    // ===== ph3: af(h1,kk1); vmcnt(0) gate (loads issued >=2 phases ago) =====
    #pragma unroll
    for (int r4 = 0; r4 < 4; ++r4)
      af[r4] = *(const short8*)(Ab + (rg * 128 + (4 + r4) * 16 + l15) * 128 + ((64 + lq * 16) ^ asw));
    if (stg) VM0();
    SB(); BAR(); LGKM0(); SB();
    __builtin_amdgcn_s_setprio(1);
    #pragma unroll
    for (int r4 = 0; r4 < 4; ++r4)
      #pragma unroll
      for (int ct = 0; ct < 4; ++ct)
        acc[4 + r4][ct] = __builtin_amdgcn_mfma_f32_16x16x32_bf16(af[r4], bf[ct], acc[4 + r4][ct], 0, 0, 0);
    __builtin_amdgcn_s_setprio(0);
    SB(); BAR();
  }

  // ---- epilogue (R3-verified): partial score over this block's 256 n-cols ----
  #pragma unroll
  for (int rt = 0; rt < 8; ++rt) {
    #pragma unroll
    for (int reg = 0; reg < 4; ++reg) {
      float sum = 0.f;
      #pragma unroll
      for (int ct = 0; ct < 4; ++ct) {
        int gn = cg * 64 + ct * 16 + l15;
        float x = qp_s[gn] + acc[rt][ct][reg];
        float e = __expf(2.f * x);
        float th = 1.f - __fdividef(2.f, e + 1.f);
        sum += va_s[gn] * th;
      }
      sum += __shfl_xor(sum, 1);
      sum += __shfl_xor(sum, 2);
      sum += __shfl_xor(sum, 4);
      sum += __shfl_xor(sum, 8);
      if (l15 == 0)
        red[rg * 128 + rt * 16 + lq * 4 + reg][cg] = sum;
    }
  }
  __syncthreads();
  if (tid < 256) {
    float s = red[tid][0] + red[tid][1] + red[tid][2] + red[tid][3];
    scores_part[((size_t)bn * NB + b) * NS + sblk * 256 + tid] = s;
  }
}

// ---- kernel 3-FALLBACK (R7, passed): f32-keys in-kernel staging ----
__global__ __launch_bounds__(512, 2)
void k_scores7(const float* __restrict__ keys, const unsigned short* __restrict__ uapk,
               const float* __restrict__ qproj, const float* __restrict__ vaw,
               float* __restrict__ scores_part) {
  __shared__ alignas(16) unsigned short Albuf[2][256 * 64];
  __shared__ alignas(16) unsigned short Blbuf[2][256 * 64];
  __shared__ float qp_s[256];
  __shared__ float va_s[256];
  __shared__ float red[256][4];
  const int sblk = blockIdx.x, bn = blockIdx.y, b = blockIdx.z;
  const int tid = threadIdx.x, w = tid >> 6, l = tid & 63;
  const int rg = w >> 2, cg = w & 3, l15 = l & 15, lq = l >> 4;
  const int asw = (l15 & 7) << 4;
  if (tid < 256) {
    qp_s[tid] = qproj[b * NH + bn * 256 + tid];
    va_s[tid] = vaw[bn * 256 + tid];
  }
  const int srow = tid >> 1, skh = tid & 1;
  const float* agbase = keys + ((size_t)b * NS + sblk * 256 + srow) * NK + skh * 32;
  const int wsw = (srow & 7) << 4;
  const char* bgbase = (const char*)uapk + (size_t)bn * 524288 + w * 4096 + l * 16;
  f32x4 acc[8][4];
  #pragma unroll
  for (int i = 0; i < 8; ++i)
    #pragma unroll
    for (int j = 0; j < 4; ++j) acc[i][j] = (f32x4){0.f, 0.f, 0.f, 0.f};
  float4 ca0, ca1, ca2, ca3, ca4, ca5, ca6, ca7;
  ca0 = *(const float4*)(agbase + 0);  ca1 = *(const float4*)(agbase + 4);
  ca2 = *(const float4*)(agbase + 8);  ca3 = *(const float4*)(agbase + 12);
  ca4 = *(const float4*)(agbase + 16); ca5 = *(const float4*)(agbase + 20);
  ca6 = *(const float4*)(agbase + 24); ca7 = *(const float4*)(agbase + 28);
  #pragma unroll
  for (int j2 = 0; j2 < 4; ++j2)
    gload16(bgbase + j2 * 1024, (char*)&Blbuf[0][0] + w * 4096 + j2 * 1024);
  {
    char* Aw = (char*)&Albuf[0][0] + srow * 128;
    uint4 q0, q1, q2, q3;
    q0.x = pk2(ca0.x, ca0.y); q0.y = pk2(ca0.z, ca0.w);
    q0.z = pk2(ca1.x, ca1.y); q0.w = pk2(ca1.z, ca1.w);
    q1.x = pk2(ca2.x, ca2.y); q1.y = pk2(ca2.z, ca2.w);
    q1.z = pk2(ca3.x, ca3.y); q1.w = pk2(ca3.z, ca3.w);
    q2.x = pk2(ca4.x, ca4.y); q2.y = pk2(ca4.z, ca4.w);
    q2.z = pk2(ca5.x, ca5.y); q2.w = pk2(ca5.z, ca5.w);
    q3.x = pk2(ca6.x, ca6.y); q3.y = pk2(ca6.z, ca6.w);
    q3.z = pk2(ca7.x, ca7.y); q3.w = pk2(ca7.z, ca7.w);
    *(uint4*)(Aw + ((skh * 64 +  0) ^ wsw)) = q0;
    *(uint4*)(Aw + ((skh * 64 + 16) ^ wsw)) = q1;
    *(uint4*)(Aw + ((skh * 64 + 32) ^ wsw)) = q2;
    *(uint4*)(Aw + ((skh * 64 + 48) ^ wsw)) = q3;
  }
  VM0(); LGKM0(); SB(); BAR();
  for (int kc = 0; kc < 16; ++kc) {
    const int cur = kc & 1;
    const char* Ab = (const char*)&Albuf[cur][0];
    const char* Bb = (const char*)&Blbuf[cur][0];
    char* Aw = (char*)&Albuf[cur ^ 1][0] + srow * 128;
    const bool stg = (kc < 15);
    short8 bf[4], af[4];
    #pragma unroll
    for (int ct = 0; ct < 4; ++ct)
      bf[ct] = *(const short8*)(Bb + (cg * 64 + ct * 16 + l15) * 128 + ((lq * 16) ^ asw));
    #pragma unroll
    for (int r4 = 0; r4 < 4; ++r4)
      af[r4] = *(const short8*)(Ab + (rg * 128 + r4 * 16 + l15) * 128 + ((lq * 16) ^ asw));
    if (stg) {
      const float* ag = agbase + (kc + 1) * 64;
      ca0 = *(const float4*)(ag + 0);  ca1 = *(const float4*)(ag + 4);
      ca2 = *(const float4*)(ag + 8);  ca3 = *(const float4*)(ag + 12);
    }
    SB(); BAR(); LGKM0(); SB();
    __builtin_amdgcn_s_setprio(1);
    #pragma unroll
    for (int r4 = 0; r4 < 4; ++r4)
      #pragma unroll
      for (int ct = 0; ct < 4; ++ct)
        acc[r4][ct] = __builtin_amdgcn_mfma_f32_16x16x32_bf16(af[r4], bf[ct], acc[r4][ct], 0, 0, 0);
    __builtin_amdgcn_s_setprio(0);
    SB(); BAR();
    #pragma unroll
    for (int r4 = 0; r4 < 4; ++r4)
      af[r4] = *(const short8*)(Ab + (rg * 128 + (4 + r4) * 16 + l15) * 128 + ((lq * 16) ^ asw));
    if (stg) {
      const float* ag = agbase + (kc + 1) * 64;
      ca4 = *(const float4*)(ag + 16); ca5 = *(const float4*)(ag + 20);
      ca6 = *(const float4*)(ag + 24); ca7 = *(const float4*)(ag + 28);
    }
    SB(); BAR(); LGKM0(); SB();
    __builtin_amdgcn_s_setprio(1);
    #pragma unroll
    for (int r4 = 0; r4 < 4; ++r4)
      #pragma unroll
      for (int ct = 0; ct < 4; ++ct)
        acc[4 + r4][ct] = __builtin_amdgcn_mfma_f32_16x16x32_bf16(af[r4], bf[ct], acc[4 + r4][ct], 0, 0, 0);
    __builtin_amdgcn_s_setprio(0);
    SB(); BAR();
    #pragma unroll
    for (int ct = 0; ct < 4; ++ct)
      bf[ct] = *(const short8*)(Bb + (cg * 64 + ct * 16 + l15) * 128 + ((64 + lq * 16) ^ asw));
    #pragma unroll
    for (int r4 = 0; r4 < 4; ++r4)
      af[r4] = *(const short8*)(Ab + (rg * 128 + r4 * 16 + l15) * 128 + ((64 + lq * 16) ^ asw));
    if (stg) {
      const char* bg = bgbase + (size_t)(kc + 1) * 32768;
      #pragma unroll
      for (int j2 = 0; j2 < 4; ++j2)
        gload16(bg + j2 * 1024, (char*)&Blbuf[cur ^ 1][0] + w * 4096 + j2 * 1024);
    }
    SB(); BAR(); LGKM0(); SB();
    __builtin_amdgcn_s_setprio(1);
    #pragma unroll
    for (int r4 = 0; r4 < 4; ++r4)
      #pragma unroll
      for (int ct = 0; ct < 4; ++ct)
        acc[r4][ct] = __builtin_amdgcn_mfma_f32_16x16x32_bf16(af[r4], bf[ct], acc[r4][ct], 0, 0, 0);
    __builtin_amdgcn_s_setprio(0);
    SB(); BAR();
    #pragma unroll
    for (int r4 = 0; r4 < 4; ++r4)
      af[r4] = *(const short8*)(Ab + (rg * 128 + (4 + r4) * 16 + l15) * 128 + ((64 + lq * 16) ^ asw));
    if (stg) {
      uint4 q0, q1, q2, q3;
      q0.x = pk2(ca0.x, ca0.y); q0.y = pk2(ca0.z, ca0.w);
      q0.z = pk2(ca1.x, ca1.y); q0.w = pk2(ca1.z, ca1.w);
      q1.x = pk2(ca2.x, ca2.y); q1.y = pk2(ca2.z, ca2.w);
      q1.z = pk2(ca3.x, ca3.y); q1.w = pk2(ca3.z, ca3.w);
      q2.x = pk2(ca4.x, ca4.y); q2.y = pk2(ca4.z, ca4.w);
      q2.z = pk2(ca5.x, ca5.y); q2.w = pk2(ca5.z, ca5.w);
      q3.x = pk2(ca6.x, ca6.y); q3.y = pk2(ca6.z, ca6.w);
      q3.z = pk2(ca7.x, ca7.y); q3.w = pk2(ca7.z, ca7.w);
      *(uint4*)(Aw + ((skh * 64 +  0) ^ wsw)) = q0;
      *(uint4*)(Aw + ((skh * 64 + 16) ^ wsw)) = q1;
      *(uint4*)(Aw + ((skh * 64 + 32) ^ wsw)) = q2;
      *(uint4*)(Aw + ((skh * 64 + 48) ^ wsw)) = q3;
      VM0();
    }
    LGKM0();
    SB(); BAR(); LGKM0(); SB();
    __builtin_amdgcn_s_setprio(1);
    #pragma unroll
    for (int r4 = 0; r4 < 4; ++r4)
      #pragma unroll
      for (int ct = 0; ct < 4; ++ct)
        acc[4 + r4][ct] = __builtin_amdgcn_mfma_f32_16x16x32_bf16(af[r4], bf[ct], acc[4 + r4][ct], 0, 0, 0);
    __builtin_amdgcn_s_setprio(0);
    SB(); BAR();
  }
  #pragma unroll
  for (int rt = 0; rt < 8; ++rt) {
    #pragma unroll
    for (int reg = 0; reg < 4; ++reg) {
      float sum = 0.f;
      #pragma unroll
      for (int ct = 0; ct < 4; ++ct) {
        int gn = cg * 64 + ct * 16 + l15;
        float x = qp_s[gn] + acc[rt][ct][reg];
        float e = __expf(2.f * x);
        float th = 1.f - __fdividef(2.f, e + 1.f);
        sum += va_s[gn] * th;
      }
      sum += __shfl_xor(sum, 1);
      sum += __shfl_xor(sum, 2);
      sum += __shfl_xor(sum, 4);
      sum += __shfl_xor(sum, 8);
      if (l15 == 0) red[rg * 128 + rt * 16 + lq * 4 + reg][cg] = sum;
    }
  }
  __syncthreads();
  if (tid < 256) {
    float s = red[tid][0] + red[tid][1] + red[tid][2] + red[tid][3];
    scores_part[((size_t)bn * NB + b) * NS + sblk * 256 + tid] = s;
  }
}

// ---- kernel 4: softmax over (part0 + part1 + vab) -> attn out ----
__global__ void k_softmax(const float* __restrict__ sp, const float* __restrict__ vab,
                          float* __restrict__ attn) {
  __shared__ float redm[4];
  __shared__ float reds[4];
  int b = blockIdx.x, tid = threadIdx.x;
  const float* r0 = sp + (size_t)b * NS;
  const float* r1 = sp + (size_t)(NB + b) * NS;
  float vb = vab[0];
  float v[16];
  float m = -1e30f;
  #pragma unroll
  for (int i = 0; i < 16; ++i) {
    int idx = i * 256 + tid;
    v[i] = r0[idx] + r1[idx] + vb;
    m = fmaxf(m, v[i]);
  }
  #pragma unroll
  for (int off = 1; off < 64; off <<= 1) m = fmaxf(m, __shfl_xor(m, off));
  if ((tid & 63) == 0) redm[tid >> 6] = m;
  __syncthreads();
  m = fmaxf(fmaxf(redm[0], redm[1]), fmaxf(redm[2], redm[3]));
  float s = 0.f;
  #pragma unroll
  for (int i = 0; i < 16; ++i) { v[i] = expf(v[i] - m); s += v[i]; }
  #pragma unroll
  for (int off = 1; off < 64; off <<= 1) s += __shfl_xor(s, off);
  if ((tid & 63) == 0) reds[tid >> 6] = s;
  __syncthreads();
  s = reds[0] + reds[1] + reds[2] + reds[3];
  float inv = 1.f / s;
  float* o = attn + (size_t)b * NS;
  #pragma unroll
  for (int i = 0; i < 16; ++i) o[i * 256 + tid] = v[i] * inv;
}

// ---- kernel 5: context partials (8 segments of 512 s-rows) ----
__global__ void k_ctx_partial(const float* __restrict__ keys, const float* __restrict__ attn,
                              float* __restrict__ part) {
  __shared__ float w_s[512];
  int b = blockIdx.y, seg = blockIdx.x, tid = threadIdx.x;
  int sbeg = seg * 512;
  w_s[tid] = attn[(size_t)b * NS + sbeg + tid];
  w_s[tid + 256] = attn[(size_t)b * NS + sbeg + 256 + tid];
  __syncthreads();
  const float* kp = keys + ((size_t)b * NS + sbeg) * NK + tid * 4;
  float ax = 0.f, ay = 0.f, az = 0.f, aw = 0.f;
  #pragma unroll 4
  for (int s = 0; s < 512; ++s) {
    float4 kv = *(const float4*)(kp + (size_t)s * NK);
    float wv = w_s[s];
    ax += wv * kv.x; ay += wv * kv.y; az += wv * kv.z; aw += wv * kv.w;
  }
  float4 o; o.x = ax; o.y = ay; o.z = az; o.w = aw;
  *(float4*)(part + ((size_t)(seg * NB + b) << 10) + tid * 4) = o;
}

// ---- kernel 6: reduce 8 segment partials -> context ----
__global__ void k_ctx_reduce(const float* __restrict__ part, float* __restrict__ ctx) {
  int i = blockIdx.x * 256 + threadIdx.x;   // 32768
  int b = i >> 10, c = i & 1023;
  float s = 0.f;
  #pragma unroll
  for (int seg = 0; seg < 8; ++seg) s += part[((size_t)(seg * NB + b) << 10) + c];
  ctx[i] = s;
}

extern "C" void kernel_launch(void* const* d_in, const int* in_sizes, int n_in,
                              void* d_out, int out_size, void* d_ws, size_t ws_size,
                              hipStream_t stream) {
  const float* query = (const float*)d_in[0];
  const float* keys  = (const float*)d_in[1];
  const float* Wa_w  = (const float*)d_in[2];
  const float* Wa_b  = (const float*)d_in[3];
  const float* Ua_w  = (const float*)d_in[4];
  const float* Ua_b  = (const float*)d_in[5];
  const float* Va_w  = (const float*)d_in[6];
  const float* Va_b  = (const float*)d_in[7];

  float* out      = (float*)d_out;
  float* ctx_out  = out;             // [32][1024]
  float* attn_out = out + NB * NK;   // [32][4096]

  unsigned short* ua_pk = (unsigned short*)d_ws;                       // 1 MB
  float* qproj  = (float*)((char*)d_ws + (1u << 20));                  // 64 KB
  float* spart  = (float*)((char*)d_ws + (1u << 20) + (1u << 16));     // 1 MB (2 partials)
  float* part   = (float*)((char*)d_ws + (2u << 20) + (1u << 16));     // 1 MB
  unsigned short* keys_pk = (unsigned short*)((char*)d_ws + (4u << 20));  // 256 MB

  const size_t need = (4ull << 20) + 268435456ull;

  k_ua_pack<<<256, 256, 0, stream>>>(Ua_w, ua_pk);
  k_qproj<<<dim3(4, NB), 128, 0, stream>>>(query, Wa_w, Wa_b, Ua_b, qproj);
  if (ws_size >= need) {
    k_keys_pack<<<65536, 256, 0, stream>>>(keys, keys_pk);
    k_scores8<<<dim3(16, 2, NB), 512, 0, stream>>>(keys_pk, ua_pk, qproj, Va_w, spart);
  } else {
    k_scores7<<<dim3(16, 2, NB), 512, 0, stream>>>(keys, ua_pk, qproj, Va_w, spart);
  }
  k_softmax<<<NB, 256, 0, stream>>>(spart, Va_b, attn_out);
  k_ctx_partial<<<dim3(8, NB), 256, 0, stream>>>(keys, attn_out, part);
  k_ctx_reduce<<<NB * NK / 256, 256, 0, stream>>>(part, ctx_out);
}